// Round 7
// baseline (16520.044 us; speedup 1.0000x reference)
//
#include <hip/hip_runtime.h>
#include <hip/hip_bf16.h>

// Decoder: attention is step-invariant (softmax shift-invariance) => ctx
// precomputed once. Persistent kernel runs the 512-step GRU recurrence.
// R11 = R9 protocol with FUSED 512-THREAD WGs (128 WGs, 32/rg):
//  - waves 0-3 = even-cg half, waves 4-7 = odd-cg half of the old pair,
//    SHARING one staged se2/sh slice and one flag => exchange L3 herd
//    halves (1MB/rg/exchange), flag posts halve, poll scans 32 lines,
//    barrier skew maxes over 32 WGs, stage burst per wave = 4KB.
//  - per-wave code byte-equivalent to R9 (w4=wave&3 = old wave,
//    cg2=cg*2+half = old cg). 8 waves x 256 VGPR = 2/SIMD -> 1 WG/CU.
// R10 post-mortem: two-tier XCD staging DEADLOCKED — leader's plain
// stores dirty only its own L2 (no write-through to L3); members fetch
// stale L3 lines -> local flag never advances. No cheap XCD-local
// publish primitive exists; abandoned.
// Carried: R9 16B sc0sc1 bursts + chunk rotation + poll backoff; R7
// per-line flags + psumB-reduce-after-sync1; R6 out(t-1) in bar2 shadow +
// __expf math. Lessons: R5 poll cheap/load once; R8 no whole-cache fences.

#define HH 1024
#define BB 64
#define LL 512
#define VV 1024

typedef short bf16x8 __attribute__((ext_vector_type(8)));
typedef float f32x4 __attribute__((ext_vector_type(4)));

__device__ __forceinline__ short f2bf(float x) {
  union { float f; unsigned u; } a; a.f = x;
  unsigned r = (a.u + 0x7FFF + ((a.u >> 16) & 1)) >> 16;
  return (short)r;
}

__device__ __forceinline__ float fsig(float x) {      // sigmoid, saturation-safe
  return 1.0f / (1.0f + __expf(-x));
}
__device__ __forceinline__ float ftanh(float x) {     // tanh, saturation-safe
  float ex = __expf(2.0f * x);
  return 1.0f - 2.0f / (ex + 1.0f);
}

// ---- coherent (cross-XCD, L3-point) access helpers ----
__device__ __forceinline__ unsigned long long ld64c(const void* p) {
  return __hip_atomic_load((const unsigned long long*)p, __ATOMIC_RELAXED, __HIP_MEMORY_SCOPE_AGENT);
}
__device__ __forceinline__ unsigned ld32c(const void* p) {
  return __hip_atomic_load((const unsigned*)p, __ATOMIC_RELAXED, __HIP_MEMORY_SCOPE_AGENT);
}
__device__ __forceinline__ void st32c(void* p, unsigned v) {
  __hip_atomic_store((unsigned*)p, v, __ATOMIC_RELAXED, __HIP_MEMORY_SCOPE_AGENT);
}
__device__ __forceinline__ void stfc(float* p, float v) {
  union { float f; unsigned u; } a; a.f = v;
  st32c(p, a.u);
}

// ---------------- workspace layout (bytes) ----------------
// FLAGS: 4 rg * 32 wg * 128B (one line per WG) = 16 KB (32KB reserved)
static constexpr size_t OFF_VE    = 0;                       // 1024 f32
static constexpr size_t OFF_ES    = 4096;                    // 64*512 f32
static constexpr size_t OFF_A     = OFF_ES    + 131072;      // 64*512 f32
static constexpr size_t OFF_CTX   = OFF_A     + 131072;      // 64*1024 f32
static constexpr size_t OFF_GICTX = OFF_CTX   + 262144;      // 64*3072 f32
static constexpr size_t OFF_OC    = OFF_GICTX + 786432;      // 64*1024 f32
static constexpr size_t OFF_FLAGS = OFF_OC    + 262144;      // one u32 / 128B line
static constexpr size_t OFF_PSUMB = OFF_FLAGS + 32768;       // 4rg*16row*64cg f32
static constexpr size_t OFF_PSUMO = OFF_PSUMB + 16384;       // 4rg*16row*64cg f32
static constexpr size_t OFF_E2    = OFF_PSUMO + 16384;       // 64*1024 bf16
static constexpr size_t OFF_HB0   = OFF_E2    + 131072;      // 64*1024 bf16
static constexpr size_t OFF_HB1   = OFF_HB0   + 131072;      // (unused)
static constexpr size_t OFF_PACKW = OFF_HB1   + 131072;      // 18 MB packed weights

// ---------------- precompute kernels ----------------

__global__ void K_init(const float* __restrict__ hidden, const float* __restrict__ dec0,
                       short* __restrict__ hb, short* __restrict__ e2,
                       unsigned* __restrict__ flags) {
  int tid = blockIdx.x * 256 + threadIdx.x;  // grid 256 -> 65536 threads
  if (tid < BB * HH) {
    hb[tid] = f2bf(hidden[tid]);
    e2[tid] = f2bf(dec0[tid]);
  }
  if (tid < 8192) flags[tid] = 0u;
}

__global__ void K_ve(const float* __restrict__ Wa, const float* __restrict__ v, float* __restrict__ ve) {
  int i = blockIdx.x * 64 + threadIdx.x;  // 1024 threads
  float acc = 0.f;
  for (int k = 0; k < HH; ++k) acc += Wa[(size_t)k * 2048 + 1024 + i] * v[k];
  ve[i] = acc;
}

__global__ void K_escore(const float* __restrict__ enc, const float* __restrict__ ve, float* __restrict__ es) {
  int bid = blockIdx.x;           // 0..32767 = l*64+b
  int lane = threadIdx.x;         // 64
  const float* row = enc + (size_t)bid * HH;
  float acc = 0.f;
  #pragma unroll
  for (int i = 0; i < 16; ++i) { int k = lane + 64 * i; acc += row[k] * ve[k]; }
  for (int m = 1; m < 64; m <<= 1) acc += __shfl_xor(acc, m);
  if (lane == 0) { int l = bid >> 6, b = bid & 63; es[b * LL + l] = acc; }
}

__global__ void K_asm(const float* __restrict__ es, float* __restrict__ a) {
  __shared__ float red[256];
  int b = blockIdx.x, tid = threadIdx.x;
  float e0 = es[b * LL + tid], e1 = es[b * LL + 256 + tid];
  red[tid] = fmaxf(e0, e1);
  __syncthreads();
  for (int s = 128; s > 0; s >>= 1) { if (tid < s) red[tid] = fmaxf(red[tid], red[tid + s]); __syncthreads(); }
  float M = red[0];
  __syncthreads();
  float x0 = expf(e0 - M), x1 = expf(e1 - M);
  red[tid] = x0 + x1;
  __syncthreads();
  for (int s = 128; s > 0; s >>= 1) { if (tid < s) red[tid] += red[tid + s]; __syncthreads(); }
  float S = red[0];
  a[b * LL + tid] = x0 / S;
  a[b * LL + 256 + tid] = x1 / S;
}

__global__ void K_ctx(const float* __restrict__ enc, const float* __restrict__ a, float* __restrict__ ctx) {
  int b = blockIdx.x >> 3, hc = blockIdx.x & 7;  // 512 blocks, 128 thr
  int h = hc * 128 + threadIdx.x;
  float acc = 0.f;
  for (int l = 0; l < LL; ++l) acc += a[b * LL + l] * enc[(size_t)(l * BB + b) * HH + h];
  ctx[b * HH + h] = acc;
}

__global__ void K_gictx(const float* __restrict__ ctx, const float* __restrict__ W_ih, const float* __restrict__ b_ih,
                        const float* __restrict__ Wo, const float* __restrict__ bo,
                        float* __restrict__ gictx, float* __restrict__ oc) {
  int c = blockIdx.x;      // 4096 blocks
  int b = threadIdx.x;     // 64 threads
  float acc = 0.f;
  if (c < 3072) {
    for (int k = 0; k < HH; ++k) acc += ctx[b * HH + k] * W_ih[(size_t)c * 2048 + 1024 + k];
    gictx[b * 3072 + c] = acc + b_ih[c];
  } else {
    int c2 = c - 3072;
    for (int k = 0; k < HH; ++k) acc += ctx[b * HH + k] * Wo[(size_t)c2 * 3072 + 2048 + k];
    oc[b * HH + c2] = acc + bo[c2];
  }
}

// Pack weights into MFMA B-fragment layout, bf16.
// tiles per col-group cg2 (16 cols): 0:gi_r(W1) 1:gi_z 2:gi_n 3:Wo_d 4:gh_r(Whh) 5:gh_z 6:gh_n 7:Wf 8:Wo_h
__global__ void K_pack(const float* __restrict__ W_ih, const float* __restrict__ W_hh,
                       const float* __restrict__ Wo, const float* __restrict__ Wf, short* __restrict__ packW) {
  int tid = blockIdx.x * 64 + threadIdx.x;   // 64*9*32*64 = 1,179,648
  int lane = tid & 63;
  int ks = (tid >> 6) & 31;
  int tile = (tid >> 11) % 9;
  int cg = tid / (9 * 32 * 64);
  int n = lane & 15;
  int k0 = ks * 32 + (lane >> 4) * 8;
  int row = cg * 16 + n;
  const float* src;
  size_t base;
  switch (tile) {
    case 0: base = (size_t)row * 2048;               src = W_ih; break;
    case 1: base = (size_t)(1024 + row) * 2048;      src = W_ih; break;
    case 2: base = (size_t)(2048 + row) * 2048;      src = W_ih; break;
    case 3: base = (size_t)row * 3072 + 1024;        src = Wo;   break;
    case 4: base = (size_t)row * 1024;               src = W_hh; break;
    case 5: base = (size_t)(1024 + row) * 1024;      src = W_hh; break;
    case 6: base = (size_t)(2048 + row) * 1024;      src = W_hh; break;
    case 7: base = (size_t)row * 1024;               src = Wf;   break;
    default: base = (size_t)row * 3072;              src = Wo;   break;
  }
  bf16x8 vv;
  #pragma unroll
  for (int j = 0; j < 8; ++j) vv[j] = f2bf(src[base + k0 + j]);
  ((bf16x8*)packW)[tid] = vv;
}

// ---------------- persistent step kernel ----------------

// Stage a 16x1024 bf16 slice (32KB) into LDS with XOR-swizzle
// byte_col ^= ((row&7)<<4). 8 waves x 4KB each; 16B sc0+sc1 bursts;
// chunk rotation by cg spreads concurrent WGs across distinct lines.
#define STAGE_SLICE(dst, srcbase)                                              \
  do {                                                                         \
    const int chunk_ = (wave + cg) & 7;                                        \
    const short* pA_ = (srcbase) + (chunk_ << 11) + (lane << 3);               \
    f32x4 t0_, t1_, t2_, t3_;                                                  \
    asm volatile(                                                              \
      "global_load_dwordx4 %0, %4, off sc0 sc1\n\t"                            \
      "global_load_dwordx4 %1, %4, off offset:1024 sc0 sc1\n\t"                \
      "global_load_dwordx4 %2, %4, off offset:2048 sc0 sc1\n\t"                \
      "global_load_dwordx4 %3, %4, off offset:3072 sc0 sc1\n\t"                \
      "s_waitcnt vmcnt(0)"                                                     \
      : "=&v"(t0_), "=&v"(t1_), "=&v"(t2_), "=&v"(t3_)                         \
      : "v"(pA_)                                                               \
      : "memory");                                                             \
    f32x4 tv_[4] = {t0_, t1_, t2_, t3_};                                       \
    _Pragma("unroll")                                                          \
    for (int i_ = 0; i_ < 4; ++i_) {                                           \
      int off_ = (chunk_ << 11) + (i_ << 9) + (lane << 3);                     \
      int r_ = off_ >> 10;                                                     \
      int sw_ = ((off_ & 1023) << 1) ^ ((r_ & 7) << 4);                        \
      *(f32x4*)&(dst)[(r_ << 10) + (sw_ >> 1)] = tv_[i_];                      \
    }                                                                          \
    __builtin_amdgcn_sched_barrier(0);                                         \
  } while (0)

// MFMA A-fragment read from swizzled LDS slice (conflict-free, 2-way max).
#define LFRAG(buf, ks) \
  (*(const bf16x8*)&(buf)[((llo) << 10) + (((((ks) * 64) + (lhi << 4)) ^ ((llo & 7) << 4)) >> 1)])

__global__ __launch_bounds__(512, 1) void K_step(
    const bf16x8* __restrict__ packW,
    short* __restrict__ e2, short* __restrict__ hb,
    const float* __restrict__ hidden,
    float* __restrict__ psumB, float* __restrict__ psumO,
    const float* __restrict__ gictx, const float* __restrict__ ocbuf,
    const float* __restrict__ b_hh, const float* __restrict__ bfv,
    float* __restrict__ outp, unsigned* __restrict__ flags) {
  const int wg = blockIdx.x;      // 128 WGs
  const int rg = wg & 3;          // row group: rows [16rg,16rg+16)
  const int cg = wg >> 2;         // [0,32): pair of col groups
  const int tid = threadIdx.x;    // [0,512)
  const int wave = tid >> 6;      // [0,8)
  const int w4 = wave & 3;        // old wave role
  const int half = wave >> 2;     // 0: cols cg*32..+16, 1: +16..+32
  const int cg2 = cg * 2 + half;  // old cg in [0,64)
  const int lane = tid & 63;
  const int lhi = lane >> 4;
  const int llo = lane & 15;

  __shared__ short se2[16 * 1024];       // e2(t) slice, swizzled (32KB)
  __shared__ short sh[16 * 1024];        // h(t)/h_new slice, swizzled (32KB)
  __shared__ float lds_g[2][6][16][17];  // per-half raw gate accs
  __shared__ float lds_p[2][5][16][17];  // per-half phase-B partials + savedA2
  __shared__ float lds_rs[16];           // 1/sum per row (shared across halves)

  const int wbase = cg2 * (9 * 32 * 64) + lane;
  const int t0 = w4 * 2, t1 = w4 * 2 + 1;

  // ---- load step-invariant weights, then FORCE them resident ----
  bf16x8 wA0[32], wA1[32], wB8[8];
  #pragma unroll
  for (int ks = 0; ks < 32; ++ks) {
    wA0[ks] = packW[wbase + (t0 * 32 + ks) * 64];
    wA1[ks] = packW[wbase + (t1 * 32 + ks) * 64];
  }
  #pragma unroll
  for (int i = 0; i < 8; ++i) wB8[i] = packW[wbase + (8 * 32 + w4 * 8 + i) * 64];
  #pragma unroll
  for (int ks = 0; ks < 32; ++ks) {
    asm volatile("" : "+v"(wA0[ks]));
    asm volatile("" : "+v"(wA1[ks]));
  }
  #pragma unroll
  for (int i = 0; i < 8; ++i) asm volatile("" : "+v"(wB8[i]));

  // ---- step-invariant per-thread scalars; h carried in-register ----
  const int row = (tid >> 4) & 15, col = tid & 15;
  const int b_ = rg * 16 + row, j = cg2 * 16 + col;
  const float c_gr  = gictx[b_ * 3072 + j]        + b_hh[j];
  const float c_gz  = gictx[b_ * 3072 + 1024 + j] + b_hh[1024 + j];
  const float c_gn  = gictx[b_ * 3072 + 2048 + j];
  const float c_ghn = b_hh[2048 + j];
  const float c_oc  = ocbuf[b_ * HH + j];
  float h_reg = hidden[b_ * HH + j];
  const float c_bf  = bfv[cg2 * 16 + llo];

  // one flag per 128B line: flags[(rg*32 + cg) * 32]
  unsigned* myflags = flags + rg * (32 * 32);
  const short* e2slice = e2 + rg * 16384;
  short*       hslice  = hb + rg * 16384;

  // pre-stage h(0) into lds (phase-B stage keeps it current afterwards)
  STAGE_SLICE(sh, hslice);

  for (int t = 0; t <= LL; ++t) {
    // ---- stage e2(t); wave0 issues the rowsum-partials gather first ----
    unsigned long long pc[8];
    if (wave == 0 && t >= 1) {
      const float* pp = psumB + rg * 1024 + llo * 64 + lhi * 16;
      #pragma unroll
      for (int i = 0; i < 8; ++i) pc[i] = ld64c(pp + i * 2);
    }
    STAGE_SLICE(se2, e2slice);
    __syncthreads();   // sync1: stage visible

    // wave0: psumB reduce + lds_rs write AFTER sync1 (hidden under other
    // waves' phase-A MFMAs; readers need lds_rs only after sync2)
    if (wave == 0) {
      float total = 1.0f;
      if (t >= 1) {
        float s = 0.f;
        #pragma unroll
        for (int i = 0; i < 8; ++i) {
          union { unsigned long long u; float f[2]; } c; c.u = pc[i];
          s += c.f[0] + c.f[1];
        }
        s += __shfl_xor(s, 16);
        s += __shfl_xor(s, 32);
        total = s;
      }
      if (lane < 16) lds_rs[lane] = 1.0f / total;
    }

    // ================= PHASE A =================
    // w4 roles: 0:{gi_r,gi_z}(A=e2) 1:{gi_n,Wo_d}(A=e2) 2:{gh_r,gh_z}(A=h) 3:{gh_n(A=h), Wf(A=e2)}
    const short* A0 = (w4 < 2) ? se2 : sh;
    f32x4 acc0 = {0.f, 0.f, 0.f, 0.f}, acc1 = {0.f, 0.f, 0.f, 0.f};
    #pragma unroll
    for (int ks = 0; ks < 32; ++ks) {
      bf16x8 af0 = LFRAG(A0, ks);
      bf16x8 af1 = (w4 == 3) ? LFRAG(se2, ks) : af0;
      acc0 = __builtin_amdgcn_mfma_f32_16x16x32_bf16(af0, wA0[ks], acc0, 0, 0, 0);
      acc1 = __builtin_amdgcn_mfma_f32_16x16x32_bf16(af1, wA1[ks], acc1, 0, 0, 0);
    }

    // stash raw accumulators to LDS (per half)
    f32x4 savedA2;
    if (w4 == 0) {
      #pragma unroll
      for (int r = 0; r < 4; ++r) { lds_g[half][0][lhi*4+r][llo] = acc0[r]; lds_g[half][1][lhi*4+r][llo] = acc1[r]; }
    } else if (w4 == 1) {
      #pragma unroll
      for (int r = 0; r < 4; ++r) { lds_g[half][2][lhi*4+r][llo] = acc0[r]; savedA2[r] = acc1[r]; }
    } else if (w4 == 2) {
      #pragma unroll
      for (int r = 0; r < 4; ++r) { lds_g[half][3][lhi*4+r][llo] = acc0[r]; lds_g[half][4][lhi*4+r][llo] = acc1[r]; }
    } else {
      #pragma unroll
      for (int r = 0; r < 4; ++r) lds_g[half][5][lhi*4+r][llo] = acc0[r];
    }
    __syncthreads();   // sync2: lds_g + lds_rs visible

    // w4==3 waves: out logits -> eo, psumO partials (distinct slots)
    f32x4 eo = {0.f, 0.f, 0.f, 0.f};
    if (w4 == 3 && t >= 1) {
      #pragma unroll
      for (int r = 0; r < 4; ++r) eo[r] = __expf(acc1[r] * lds_rs[lhi*4+r] + c_bf);
      #pragma unroll
      for (int r = 0; r < 4; ++r) {
        float v_ = eo[r];
        v_ += __shfl_xor(v_, 1, 16); v_ += __shfl_xor(v_, 2, 16);
        v_ += __shfl_xor(v_, 4, 16); v_ += __shfl_xor(v_, 8, 16);
        if (llo == 0) stfc(psumO + rg * 1024 + (lhi*4+r) * 64 + cg2, v_);
      }
    }

    // GRU elementwise: thread (half,row,col) owns h[b_,j]
    {
      float rsr = lds_rs[row];
      float gr  = lds_g[half][0][row][col] * rsr + lds_g[half][3][row][col] + c_gr;
      float gz  = lds_g[half][1][row][col] * rsr + lds_g[half][4][row][col] + c_gz;
      float gin = lds_g[half][2][row][col] * rsr + c_gn;
      float ghn = lds_g[half][5][row][col] + c_ghn;
      float rr = fsig(gr);
      float zz = fsig(gz);
      float nn = ftanh(gin + rr * ghn);
      float hnew = (1.0f - zz) * nn + zz * h_reg;
      h_reg = hnew;
      unsigned short hv = (unsigned short)f2bf(hnew);
      int other = __shfl_xor((int)hv, 1);
      if ((col & 1) == 0) {
        unsigned pk = (unsigned)hv | ((unsigned)(unsigned short)other << 16);
        st32c(hb + b_ * HH + (j & ~1), pk);
      }
    }

    // ---- bar1: h_new + psumO visible (flag barrier, rg-local) ----
    {
      unsigned ep = 2u * (unsigned)t + 1u;
      __syncthreads();                  // drains each wave's stores
      if (tid == 0) st32c(myflags + cg * 32, ep);
      if (wave == 0) {
        unsigned f;
        for (;;) {
          f = ld32c(myflags + (lane & 31) * 32);
          if (!__any(f < ep)) break;
          __builtin_amdgcn_s_sleep(1);
        }
      }
      __syncthreads();
    }

    // ================= PHASE B =================
    if (t < LL) {
      STAGE_SLICE(sh, hslice);          // h(t+1) -> lds (also next phase A)
      __syncthreads();
      f32x4 accB = {0.f, 0.f, 0.f, 0.f};
      #pragma unroll
      for (int i = 0; i < 8; ++i) {
        int ks = w4 * 8 + i;
        bf16x8 af = LFRAG(sh, ks);
        accB = __builtin_amdgcn_mfma_f32_16x16x32_bf16(af, wB8[i], accB, 0, 0, 0);
      }
      #pragma unroll
      for (int r = 0; r < 4; ++r) lds_p[half][w4][lhi*4+r][llo] = accB[r];
      if (w4 == 1) {
        #pragma unroll
        for (int r = 0; r < 4; ++r) lds_p[half][4][lhi*4+r][llo] = savedA2[r];
      }
      __syncthreads();
      {
        float rsr = lds_rs[row];
        float l2 = lds_p[half][0][row][col] + lds_p[half][1][row][col] + lds_p[half][2][row][col]
                 + lds_p[half][3][row][col] + lds_p[half][4][row][col] * rsr + c_oc;
        float ev = __expf(l2);
        unsigned short eb = (unsigned short)f2bf(ev);
        int other = __shfl_xor((int)eb, 1);
        if ((col & 1) == 0) {
          unsigned pk = (unsigned)eb | ((unsigned)(unsigned short)other << 16);
          st32c(e2 + b_ * HH + (j & ~1), pk);
        }
        float sv = ev;
        sv += __shfl_xor(sv, 1, 16); sv += __shfl_xor(sv, 2, 16);
        sv += __shfl_xor(sv, 4, 16); sv += __shfl_xor(sv, 8, 16);
        if (col == 0) stfc(psumB + rg * 1024 + row * 64 + cg2, sv);
      }

      // ---- bar2: e2 + psumB visible; out(t-1) hidden in the poll shadow ----
      {
        unsigned ep = 2u * (unsigned)t + 2u;
        __syncthreads();                 // drains e2 + psumB stores
        if (tid == 0) st32c(myflags + cg * 32, ep);
        // out(t-1): w4==3 waves reduce psumO (posted+drained at bar1) and
        // store the output rows, overlapped with wave0's flag poll.
        if (t >= 1 && w4 == 3) {
          #pragma unroll
          for (int r = 0; r < 4; ++r) {
            int prow = lhi * 4 + r;
            const float* pp = psumO + rg * 1024 + prow * 64 + llo * 4;
            union { unsigned long long u; float f[2]; } c0, c1;
            c0.u = ld64c(pp); c1.u = ld64c(pp + 2);
            float s = c0.f[0] + c0.f[1] + c1.f[0] + c1.f[1];
            s += __shfl_xor(s, 1, 16); s += __shfl_xor(s, 2, 16);
            s += __shfl_xor(s, 4, 16); s += __shfl_xor(s, 8, 16);
            int b2 = rg * 16 + prow;
            outp[(size_t)(t - 1) * BB * VV + (size_t)b2 * VV + cg2 * 16 + llo] = eo[r] / s;
          }
        }
        if (wave == 0) {
          unsigned f;
          for (;;) {
            f = ld32c(myflags + (lane & 31) * 32);
            if (!__any(f < ep)) break;
            __builtin_amdgcn_s_sleep(1);
          }
        }
        __syncthreads();
      }
    } else {
      // t == LL: no phase B / bar2 — emit final out(LL-1) directly
      if (w4 == 3) {
        #pragma unroll
        for (int r = 0; r < 4; ++r) {
          int prow = lhi * 4 + r;
          const float* pp = psumO + rg * 1024 + prow * 64 + llo * 4;
          union { unsigned long long u; float f[2]; } c0, c1;
          c0.u = ld64c(pp); c1.u = ld64c(pp + 2);
          float s = c0.f[0] + c0.f[1] + c1.f[0] + c1.f[1];
          s += __shfl_xor(s, 1, 16); s += __shfl_xor(s, 2, 16);
          s += __shfl_xor(s, 4, 16); s += __shfl_xor(s, 8, 16);
          int b2 = rg * 16 + prow;
          outp[(size_t)(t - 1) * BB * VV + (size_t)b2 * VV + cg2 * 16 + llo] = eo[r] / s;
        }
      }
    }
  }
}

// ---------------- host launcher ----------------

extern "C" void kernel_launch(void* const* d_in, const int* in_sizes, int n_in,
                              void* d_out, int out_size, void* d_ws, size_t ws_size,
                              hipStream_t stream) {
  (void)in_sizes; (void)n_in; (void)out_size; (void)ws_size;
  const float* enc    = (const float*)d_in[0];
  const float* hidden = (const float*)d_in[1];
  const float* dec0   = (const float*)d_in[2];
  const float* Wa     = (const float*)d_in[3];
  // d_in[4] = ba: unused (softmax shift-invariance)
  const float* v      = (const float*)d_in[5];
  const float* W_ih   = (const float*)d_in[6];
  const float* b_ih   = (const float*)d_in[7];
  const float* W_hh   = (const float*)d_in[8];
  const float* b_hh   = (const float*)d_in[9];
  const float* Wo     = (const float*)d_in[10];
  const float* bo     = (const float*)d_in[11];
  const float* Wf     = (const float*)d_in[12];
  const float* bfv    = (const float*)d_in[13];

  char* ws = (char*)d_ws;
  float* ve    = (float*)(ws + OFF_VE);
  float* es    = (float*)(ws + OFF_ES);
  float* attn  = (float*)(ws + OFF_A);
  float* ctx   = (float*)(ws + OFF_CTX);
  float* gictx = (float*)(ws + OFF_GICTX);
  float* oc    = (float*)(ws + OFF_OC);
  unsigned* flags = (unsigned*)(ws + OFF_FLAGS);
  float* psumB = (float*)(ws + OFF_PSUMB);
  float* psumO = (float*)(ws + OFF_PSUMO);
  short* e2    = (short*)(ws + OFF_E2);
  short* hb    = (short*)(ws + OFF_HB0);
  short* packW = (short*)(ws + OFF_PACKW);

  hipLaunchKernelGGL(K_init, dim3(256), dim3(256), 0, stream, hidden, dec0, hb, e2, flags);
  hipLaunchKernelGGL(K_ve, dim3(16), dim3(64), 0, stream, Wa, v, ve);
  hipLaunchKernelGGL(K_escore, dim3(LL * BB), dim3(64), 0, stream, enc, ve, es);
  hipLaunchKernelGGL(K_asm, dim3(BB), dim3(256), 0, stream, es, attn);
  hipLaunchKernelGGL(K_ctx, dim3(512), dim3(128), 0, stream, enc, attn, ctx);
  hipLaunchKernelGGL(K_gictx, dim3(4096), dim3(64), 0, stream, ctx, W_ih, b_ih, Wo, bo, gictx, oc);
  hipLaunchKernelGGL(K_pack, dim3(64 * 9 * 32), dim3(64), 0, stream, W_ih, W_hh, Wo, Wf, packW);
  hipLaunchKernelGGL(K_step, dim3(128), dim3(512), 0, stream,
                     (const bf16x8*)packW, e2, hb, hidden, psumB, psumO,
                     gictx, oc, b_hh, bfv, (float*)d_out, flags);
}

// Round 8
// 6518.235 us; speedup vs baseline: 2.5344x; 2.5344x over previous
//
#include <hip/hip_runtime.h>
#include <hip/hip_bf16.h>

// Decoder: attention is step-invariant (softmax shift-invariance) => ctx
// precomputed once. Persistent kernel runs the 512-step GRU recurrence.
// R12 = R9 with BARRIERS FOLDED INTO PER-WAVE GATED STAGES:
//  - each staged 32KB slice is chunked by SOURCE-CG blocks (16 cgs = 256
//    cols per wave); a wave polls only its 16 source flags then loads its
//    chunk. The poll IS the gate: the two post-poll __syncthreads of R9
//    are gone (8 -> 6 syncs/step) and loads start at per-source arrival,
//    not the global max.
//  - wave0 polls all-64 at the A-gate (needs all for psumB; also provides
//    the collective certification the reuse proofs need).
//  - e2 + psumB parity DOUBLE-BUFFERED (producers no longer observe an
//    all-64 bar1; writer of EB[par^1] at t passed all-64 bar2(t-1) =>
//    every WG finished its A-stage(t-1) read of EB[par^1]). h stays
//    single-buffered (reads gated on exact source flags; overwrite at
//    GRU(t) ordered behind all-64 bar2(t-1)).
//  - out(t-1): psumO gather issued right after the h-stage sync (psumO
//    collectively certified there), reduced after the e2 posts, stored
//    NONTEMPORAL -> write-allocate RMW fetches avoided and the drain sits
//    behind phase B instead of on bar2's flag post.
// R11 post-mortem: fused 512-thread WGs force 2 waves/SIMD = 256-reg
// budget < 288 weight regs -> spill, 12GB scratch traffic, 3.3x slower.
// Topology is pinned by weight residency. Carried: R9 16B sc0sc1 bursts +
// rotation + poll backoff; R7 per-line flags; R6 __expf. Lessons: R5 poll
// cheap/load once; R8 no whole-cache fences; R10 no plain-store publish.

#define HH 1024
#define BB 64
#define LL 512
#define VV 1024

typedef short bf16x8 __attribute__((ext_vector_type(8)));
typedef float f32x4 __attribute__((ext_vector_type(4)));

__device__ __forceinline__ short f2bf(float x) {
  union { float f; unsigned u; } a; a.f = x;
  unsigned r = (a.u + 0x7FFF + ((a.u >> 16) & 1)) >> 16;
  return (short)r;
}

__device__ __forceinline__ float fsig(float x) {      // sigmoid, saturation-safe
  return 1.0f / (1.0f + __expf(-x));
}
__device__ __forceinline__ float ftanh(float x) {     // tanh, saturation-safe
  float ex = __expf(2.0f * x);
  return 1.0f - 2.0f / (ex + 1.0f);
}

// ---- coherent (cross-XCD, L3-point) access helpers ----
__device__ __forceinline__ unsigned long long ld64c(const void* p) {
  return __hip_atomic_load((const unsigned long long*)p, __ATOMIC_RELAXED, __HIP_MEMORY_SCOPE_AGENT);
}
__device__ __forceinline__ unsigned ld32c(const void* p) {
  return __hip_atomic_load((const unsigned*)p, __ATOMIC_RELAXED, __HIP_MEMORY_SCOPE_AGENT);
}
__device__ __forceinline__ void st32c(void* p, unsigned v) {
  __hip_atomic_store((unsigned*)p, v, __ATOMIC_RELAXED, __HIP_MEMORY_SCOPE_AGENT);
}
__device__ __forceinline__ void stfc(float* p, float v) {
  union { float f; unsigned u; } a; a.f = v;
  st32c(p, a.u);
}

// ---------------- workspace layout (bytes) ----------------
// FLAGS: 4 rg * 64 cg * 128B (one line per WG) = 32 KB
static constexpr size_t OFF_VE    = 0;                       // 1024 f32
static constexpr size_t OFF_ES    = 4096;                    // 64*512 f32
static constexpr size_t OFF_A     = OFF_ES    + 131072;      // 64*512 f32
static constexpr size_t OFF_CTX   = OFF_A     + 131072;      // 64*1024 f32
static constexpr size_t OFF_GICTX = OFF_CTX   + 262144;      // 64*3072 f32
static constexpr size_t OFF_OC    = OFF_GICTX + 786432;      // 64*1024 f32
static constexpr size_t OFF_FLAGS = OFF_OC    + 262144;      // 8192 u32 (one/128B)
static constexpr size_t OFF_PSUMB = OFF_FLAGS + 32768;       // 2 x 4096 f32 (parity)
static constexpr size_t OFF_PSUMO = OFF_PSUMB + 32768;       // 4rg*16row*64cg f32
static constexpr size_t OFF_E2A   = OFF_PSUMO + 16384;       // 64*1024 bf16 (EB0)
static constexpr size_t OFF_HB    = OFF_E2A   + 131072;      // 64*1024 bf16 (h)
static constexpr size_t OFF_E2B   = OFF_HB    + 131072;      // 64*1024 bf16 (EB1)
static constexpr size_t OFF_PACKW = OFF_E2B   + 131072;      // 18 MB packed weights

// ---------------- precompute kernels ----------------

__global__ void K_init(const float* __restrict__ hidden, const float* __restrict__ dec0,
                       short* __restrict__ hb, short* __restrict__ e2a,
                       unsigned* __restrict__ flags) {
  int tid = blockIdx.x * 256 + threadIdx.x;  // grid 256 -> 65536 threads
  if (tid < BB * HH) {
    hb[tid] = f2bf(hidden[tid]);
    e2a[tid] = f2bf(dec0[tid]);
  }
  if (tid < 8192) flags[tid] = 0u;
}

__global__ void K_ve(const float* __restrict__ Wa, const float* __restrict__ v, float* __restrict__ ve) {
  int i = blockIdx.x * 64 + threadIdx.x;  // 1024 threads
  float acc = 0.f;
  for (int k = 0; k < HH; ++k) acc += Wa[(size_t)k * 2048 + 1024 + i] * v[k];
  ve[i] = acc;
}

__global__ void K_escore(const float* __restrict__ enc, const float* __restrict__ ve, float* __restrict__ es) {
  int bid = blockIdx.x;           // 0..32767 = l*64+b
  int lane = threadIdx.x;         // 64
  const float* row = enc + (size_t)bid * HH;
  float acc = 0.f;
  #pragma unroll
  for (int i = 0; i < 16; ++i) { int k = lane + 64 * i; acc += row[k] * ve[k]; }
  for (int m = 1; m < 64; m <<= 1) acc += __shfl_xor(acc, m);
  if (lane == 0) { int l = bid >> 6, b = bid & 63; es[b * LL + l] = acc; }
}

__global__ void K_asm(const float* __restrict__ es, float* __restrict__ a) {
  __shared__ float red[256];
  int b = blockIdx.x, tid = threadIdx.x;
  float e0 = es[b * LL + tid], e1 = es[b * LL + 256 + tid];
  red[tid] = fmaxf(e0, e1);
  __syncthreads();
  for (int s = 128; s > 0; s >>= 1) { if (tid < s) red[tid] = fmaxf(red[tid], red[tid + s]); __syncthreads(); }
  float M = red[0];
  __syncthreads();
  float x0 = expf(e0 - M), x1 = expf(e1 - M);
  red[tid] = x0 + x1;
  __syncthreads();
  for (int s = 128; s > 0; s >>= 1) { if (tid < s) red[tid] += red[tid + s]; __syncthreads(); }
  float S = red[0];
  a[b * LL + tid] = x0 / S;
  a[b * LL + 256 + tid] = x1 / S;
}

__global__ void K_ctx(const float* __restrict__ enc, const float* __restrict__ a, float* __restrict__ ctx) {
  int b = blockIdx.x >> 3, hc = blockIdx.x & 7;  // 512 blocks, 128 thr
  int h = hc * 128 + threadIdx.x;
  float acc = 0.f;
  for (int l = 0; l < LL; ++l) acc += a[b * LL + l] * enc[(size_t)(l * BB + b) * HH + h];
  ctx[b * HH + h] = acc;
}

__global__ void K_gictx(const float* __restrict__ ctx, const float* __restrict__ W_ih, const float* __restrict__ b_ih,
                        const float* __restrict__ Wo, const float* __restrict__ bo,
                        float* __restrict__ gictx, float* __restrict__ oc) {
  int c = blockIdx.x;      // 4096 blocks
  int b = threadIdx.x;     // 64 threads
  float acc = 0.f;
  if (c < 3072) {
    for (int k = 0; k < HH; ++k) acc += ctx[b * HH + k] * W_ih[(size_t)c * 2048 + 1024 + k];
    gictx[b * 3072 + c] = acc + b_ih[c];
  } else {
    int c2 = c - 3072;
    for (int k = 0; k < HH; ++k) acc += ctx[b * HH + k] * Wo[(size_t)c2 * 3072 + 2048 + k];
    oc[b * HH + c2] = acc + bo[c2];
  }
}

// Pack weights into MFMA B-fragment layout, bf16.
// tiles per col-group cg (16 cols): 0:gi_r(W1) 1:gi_z 2:gi_n 3:Wo_d 4:gh_r(Whh) 5:gh_z 6:gh_n 7:Wf 8:Wo_h
__global__ void K_pack(const float* __restrict__ W_ih, const float* __restrict__ W_hh,
                       const float* __restrict__ Wo, const float* __restrict__ Wf, short* __restrict__ packW) {
  int tid = blockIdx.x * 64 + threadIdx.x;   // 64*9*32*64 = 1,179,648
  int lane = tid & 63;
  int ks = (tid >> 6) & 31;
  int tile = (tid >> 11) % 9;
  int cg = tid / (9 * 32 * 64);
  int n = lane & 15;
  int k0 = ks * 32 + (lane >> 4) * 8;
  int row = cg * 16 + n;
  const float* src;
  size_t base;
  switch (tile) {
    case 0: base = (size_t)row * 2048;               src = W_ih; break;
    case 1: base = (size_t)(1024 + row) * 2048;      src = W_ih; break;
    case 2: base = (size_t)(2048 + row) * 2048;      src = W_ih; break;
    case 3: base = (size_t)row * 3072 + 1024;        src = Wo;   break;
    case 4: base = (size_t)row * 1024;               src = W_hh; break;
    case 5: base = (size_t)(1024 + row) * 1024;      src = W_hh; break;
    case 6: base = (size_t)(2048 + row) * 1024;      src = W_hh; break;
    case 7: base = (size_t)row * 1024;               src = Wf;   break;
    default: base = (size_t)row * 3072;              src = Wo;   break;
  }
  bf16x8 vv;
  #pragma unroll
  for (int j = 0; j < 8; ++j) vv[j] = f2bf(src[base + k0 + j]);
  ((bf16x8*)packW)[tid] = vv;
}

// ---------------- persistent step kernel ----------------

// Stage one 16-row x 256-col (16-cg) block of a slice into LDS with
// XOR-swizzle byte_col ^= ((row&7)<<4). Per lane: 128B contiguous of one
// row (row = lane>>2), 8 x dwordx4 at offsets 0..112. sc0+sc1 bypass.
#define STAGE_BLOCK(dst, srcbase, blk)                                         \
  do {                                                                         \
    const int r_ = lane >> 2;                                                  \
    const int co_ = ((blk) << 8) + ((lane & 3) << 6);   /* shorts in row */    \
    const short* p_ = (srcbase) + (r_ << 10) + co_;                            \
    f32x4 t0_, t1_, t2_, t3_, t4_, t5_, t6_, t7_;                              \
    asm volatile(                                                              \
      "global_load_dwordx4 %0, %8, off sc0 sc1\n\t"                            \
      "global_load_dwordx4 %1, %8, off offset:16 sc0 sc1\n\t"                  \
      "global_load_dwordx4 %2, %8, off offset:32 sc0 sc1\n\t"                  \
      "global_load_dwordx4 %3, %8, off offset:48 sc0 sc1\n\t"                  \
      "global_load_dwordx4 %4, %8, off offset:64 sc0 sc1\n\t"                  \
      "global_load_dwordx4 %5, %8, off offset:80 sc0 sc1\n\t"                  \
      "global_load_dwordx4 %6, %8, off offset:96 sc0 sc1\n\t"                  \
      "global_load_dwordx4 %7, %8, off offset:112 sc0 sc1\n\t"                 \
      "s_waitcnt vmcnt(0)"                                                     \
      : "=&v"(t0_), "=&v"(t1_), "=&v"(t2_), "=&v"(t3_),                        \
        "=&v"(t4_), "=&v"(t5_), "=&v"(t6_), "=&v"(t7_)                         \
      : "v"(p_)                                                                \
      : "memory");                                                             \
    f32x4 tv_[8] = {t0_, t1_, t2_, t3_, t4_, t5_, t6_, t7_};                   \
    _Pragma("unroll")                                                          \
    for (int i_ = 0; i_ < 8; ++i_) {                                           \
      int bc_ = (co_ + (i_ << 3)) << 1;                                        \
      int sw_ = bc_ ^ ((r_ & 7) << 4);                                         \
      *(f32x4*)&(dst)[(r_ << 10) + (sw_ >> 1)] = tv_[i_];                      \
    }                                                                          \
    __builtin_amdgcn_sched_barrier(0);                                         \
  } while (0)

// Poll the 16 source-cg flags of block blk (4-way redundant across lanes).
#define POLL16(flg, blk, ep)                                                   \
  do {                                                                         \
    unsigned f_;                                                               \
    for (;;) {                                                                 \
      f_ = ld32c((flg) + ((blk) * 16 + (lane & 15)) * 32);                     \
      if (!__any(f_ < (unsigned)(ep))) break;                                  \
      __builtin_amdgcn_s_sleep(1);                                             \
    }                                                                          \
  } while (0)

// Poll all 64 flags (one line per lane).
#define POLL64(flg, ep)                                                        \
  do {                                                                         \
    unsigned f_;                                                               \
    for (;;) {                                                                 \
      f_ = ld32c((flg) + lane * 32);                                           \
      if (!__any(f_ < (unsigned)(ep))) break;                                  \
      __builtin_amdgcn_s_sleep(1);                                             \
    }                                                                          \
  } while (0)

// MFMA A-fragment read from swizzled LDS slice (conflict-free, 2-way max).
#define LFRAG(buf, ks) \
  (*(const bf16x8*)&(buf)[((llo) << 10) + (((((ks) * 64) + (lhi << 4)) ^ ((llo & 7) << 4)) >> 1)])

__global__ __launch_bounds__(256, 1) void K_step(
    const bf16x8* __restrict__ packW,
    short* __restrict__ e2a, short* __restrict__ e2b,
    short* __restrict__ hb,
    const float* __restrict__ hidden,
    float* __restrict__ psumB, float* __restrict__ psumO,
    const float* __restrict__ gictx, const float* __restrict__ ocbuf,
    const float* __restrict__ b_hh, const float* __restrict__ bfv,
    float* __restrict__ outp, unsigned* __restrict__ flags) {
  const int wg = blockIdx.x;
  const int rg = wg & 3;      // row group: rows [16rg,16rg+16)
  const int cg = wg >> 2;     // col group: 16 cols of each output tile
  const int tid = threadIdx.x;
  const int wave = tid >> 6;
  const int lane = tid & 63;
  const int lhi = lane >> 4;
  const int llo = lane & 15;
  const int blk = (wave + cg) & 3;   // rotated source-cg block

  __shared__ short se2[16 * 1024];    // e2(t) slice, swizzled (32KB)
  __shared__ short sh[16 * 1024];     // h(t)/h_new slice, swizzled (32KB)
  __shared__ float lds_g[6][16][17];  // raw gate accs: gi_r gi_z gi_n gh_r gh_z gh_n
  __shared__ float lds_p[5][16][17];  // phase-B partials [0..3] + savedA2 [4]
  __shared__ float lds_rs[16];        // 1/sum per row (e2 normalization)

  const int wbase = cg * (9 * 32 * 64) + lane;
  const int t0 = wave * 2, t1 = wave * 2 + 1;

  // ---- load step-invariant weights, then FORCE them resident ----
  bf16x8 wA0[32], wA1[32], wB8[8];
  #pragma unroll
  for (int ks = 0; ks < 32; ++ks) {
    wA0[ks] = packW[wbase + (t0 * 32 + ks) * 64];
    wA1[ks] = packW[wbase + (t1 * 32 + ks) * 64];
  }
  #pragma unroll
  for (int i = 0; i < 8; ++i) wB8[i] = packW[wbase + (8 * 32 + wave * 8 + i) * 64];
  #pragma unroll
  for (int ks = 0; ks < 32; ++ks) {
    asm volatile("" : "+v"(wA0[ks]));
    asm volatile("" : "+v"(wA1[ks]));
  }
  #pragma unroll
  for (int i = 0; i < 8; ++i) asm volatile("" : "+v"(wB8[i]));

  // ---- step-invariant per-thread scalars; h carried in-register ----
  const int row = tid >> 4, col = tid & 15;
  const int b_ = rg * 16 + row, j = cg * 16 + col;
  const float c_gr  = gictx[b_ * 3072 + j]        + b_hh[j];
  const float c_gz  = gictx[b_ * 3072 + 1024 + j] + b_hh[1024 + j];
  const float c_gn  = gictx[b_ * 3072 + 2048 + j];
  const float c_ghn = b_hh[2048 + j];
  const float c_oc  = ocbuf[b_ * HH + j];
  float h_reg = hidden[b_ * HH + j];
  const float c_bf  = bfv[cg * 16 + llo];

  // one flag per 128B line: flags[(rg*64 + cg) * 32]
  unsigned* myflags = flags + rg * (64 * 32);
  short* hslice = hb + rg * 16384;

  // pre-stage h(0) into lds (B-stage keeps it current afterwards)
  STAGE_BLOCK(sh, hslice, blk);

  for (int t = 0; t <= LL; ++t) {
    const int par = t & 1;
    const short* ebr = (par ? e2b : e2a) + rg * 16384;  // EB[par]: e2(t)
    short* ebw = par ? e2a : e2b;                        // EB[par^1]: e2(t+1)
    const float* PBr = psumB + par * 4096 + rg * 1024;
    float* PBw = psumB + (par ^ 1) * 4096 + rg * 1024;

    // ======== A-gate + stage e2(t) ========
    unsigned long long pc[8];
    if (wave == 0) {
      POLL64(myflags, 2u * (unsigned)t);          // bar2(t-1), all 64
      if (t >= 1) {
        const float* pp = PBr + llo * 64 + lhi * 16;
        #pragma unroll
        for (int i = 0; i < 8; ++i) pc[i] = ld64c(pp + i * 2);
      }
      STAGE_BLOCK(se2, ebr, blk);
    } else {
      POLL16(myflags, blk, 2u * (unsigned)t);     // only this block's sources
      STAGE_BLOCK(se2, ebr, blk);
    }
    __syncthreads();   // S1: all 4 blocks staged; collective all-64 via wave0

    // wave0: psumB reduce + lds_rs (hidden under other waves' phase-A MFMAs)
    if (wave == 0) {
      float total = 1.0f;
      if (t >= 1) {
        float s = 0.f;
        #pragma unroll
        for (int i = 0; i < 8; ++i) {
          union { unsigned long long u; float f[2]; } c; c.u = pc[i];
          s += c.f[0] + c.f[1];
        }
        s += __shfl_xor(s, 16);
        s += __shfl_xor(s, 32);
        total = s;
      }
      if (lane < 16) lds_rs[lane] = 1.0f / total;
    }

    // ================= PHASE A =================
    // waves: 0:{gi_r,gi_z}(A=e2) 1:{gi_n,Wo_d}(A=e2) 2:{gh_r,gh_z}(A=h) 3:{gh_n(A=h), Wf(A=e2)}
    const short* A0 = (wave < 2) ? se2 : sh;
    f32x4 acc0 = {0.f, 0.f, 0.f, 0.f}, acc1 = {0.f, 0.f, 0.f, 0.f};
    #pragma unroll
    for (int ks = 0; ks < 32; ++ks) {
      bf16x8 af0 = LFRAG(A0, ks);
      bf16x8 af1 = (wave == 3) ? LFRAG(se2, ks) : af0;
      acc0 = __builtin_amdgcn_mfma_f32_16x16x32_bf16(af0, wA0[ks], acc0, 0, 0, 0);
      acc1 = __builtin_amdgcn_mfma_f32_16x16x32_bf16(af1, wA1[ks], acc1, 0, 0, 0);
    }

    // stash raw accumulators to LDS
    f32x4 savedA2;
    if (wave == 0) {
      #pragma unroll
      for (int r = 0; r < 4; ++r) { lds_g[0][lhi*4+r][llo] = acc0[r]; lds_g[1][lhi*4+r][llo] = acc1[r]; }
    } else if (wave == 1) {
      #pragma unroll
      for (int r = 0; r < 4; ++r) { lds_g[2][lhi*4+r][llo] = acc0[r]; savedA2[r] = acc1[r]; }
    } else if (wave == 2) {
      #pragma unroll
      for (int r = 0; r < 4; ++r) { lds_g[3][lhi*4+r][llo] = acc0[r]; lds_g[4][lhi*4+r][llo] = acc1[r]; }
    } else {
      #pragma unroll
      for (int r = 0; r < 4; ++r) lds_g[5][lhi*4+r][llo] = acc0[r];
    }
    __syncthreads();   // S2: lds_g + lds_rs visible

    // wave3: out logits -> eo, psumO partials (distinct slots, no atomics)
    f32x4 eo = {0.f, 0.f, 0.f, 0.f};
    if (wave == 3 && t >= 1) {
      #pragma unroll
      for (int r = 0; r < 4; ++r) eo[r] = __expf(acc1[r] * lds_rs[lhi*4+r] + c_bf);
      #pragma unroll
      for (int r = 0; r < 4; ++r) {
        float v_ = eo[r];
        v_ += __shfl_xor(v_, 1, 16); v_ += __shfl_xor(v_, 2, 16);
        v_ += __shfl_xor(v_, 4, 16); v_ += __shfl_xor(v_, 8, 16);
        if (llo == 0) stfc(psumO + rg * 1024 + (lhi*4+r) * 64 + cg, v_);
      }
    }

    // GRU elementwise: thread (row,col) owns h[b_,j]
    {
      float rsr = lds_rs[row];
      float gr  = lds_g[0][row][col] * rsr + lds_g[3][row][col] + c_gr;
      float gz  = lds_g[1][row][col] * rsr + lds_g[4][row][col] + c_gz;
      float gin = lds_g[2][row][col] * rsr + c_gn;
      float ghn = lds_g[5][row][col] + c_ghn;
      float rr = fsig(gr);
      float zz = fsig(gz);
      float nn = ftanh(gin + rr * ghn);
      float hnew = (1.0f - zz) * nn + zz * h_reg;
      h_reg = hnew;
      unsigned short hv = (unsigned short)f2bf(hnew);
      int other = __shfl_xor((int)hv, 1);
      if ((col & 1) == 0) {
        unsigned pk = (unsigned)hv | ((unsigned)(unsigned short)other << 16);
        st32c(hb + b_ * HH + (j & ~1), pk);
      }
    }

    // ---- bar1 post: h_new + psumO drained, flag = 2t+1 ----
    __syncthreads();   // S3: drains h + psumO stores
    if (tid == 0) st32c(myflags + cg * 32, 2u * (unsigned)t + 1u);

    if (t < LL) {
      // ======== B-gate + stage h(t+1) ========
      POLL16(myflags, blk, 2u * (unsigned)t + 1u);
      STAGE_BLOCK(sh, hslice, blk);
      __syncthreads();   // S5: staged; collective all-64 bar1(t) via 4 blocks

      // wave3: issue psumO(t) gather early (certified collectively at S5);
      // reduce + nt-store after the e2 posts, drained at S7 behind phase B.
      union { unsigned long long u; float f[2]; } g0[4], g1[4];
      if (wave == 3 && t >= 1) {
        #pragma unroll
        for (int r = 0; r < 4; ++r) {
          const float* pp = psumO + rg * 1024 + (lhi * 4 + r) * 64 + llo * 4;
          g0[r].u = ld64c(pp);
          g1[r].u = ld64c(pp + 2);
        }
      }

      // ================= PHASE B =================
      f32x4 accB = {0.f, 0.f, 0.f, 0.f};
      #pragma unroll
      for (int i = 0; i < 8; ++i) {
        int ks = wave * 8 + i;
        bf16x8 af = LFRAG(sh, ks);
        accB = __builtin_amdgcn_mfma_f32_16x16x32_bf16(af, wB8[i], accB, 0, 0, 0);
      }
      #pragma unroll
      for (int r = 0; r < 4; ++r) lds_p[wave][lhi*4+r][llo] = accB[r];
      if (wave == 1) {
        #pragma unroll
        for (int r = 0; r < 4; ++r) lds_p[4][lhi*4+r][llo] = savedA2[r];
      }
      __syncthreads();   // S6: lds_p visible
      {
        float rsr = lds_rs[row];
        float l2 = lds_p[0][row][col] + lds_p[1][row][col] + lds_p[2][row][col] + lds_p[3][row][col]
                 + lds_p[4][row][col] * rsr + c_oc;
        float ev = __expf(l2);
        unsigned short eb = (unsigned short)f2bf(ev);
        int other = __shfl_xor((int)eb, 1);
        if ((col & 1) == 0) {
          unsigned pk = (unsigned)eb | ((unsigned)(unsigned short)other << 16);
          st32c(ebw + b_ * HH + (j & ~1), pk);
        }
        float sv = ev;
        sv += __shfl_xor(sv, 1, 16); sv += __shfl_xor(sv, 2, 16);
        sv += __shfl_xor(sv, 4, 16); sv += __shfl_xor(sv, 8, 16);
        if (col == 0) stfc(PBw + row * 64 + cg, sv);
      }

      // out(t-1): reduce prefetched psumO, nontemporal store
      if (wave == 3 && t >= 1) {
        #pragma unroll
        for (int r = 0; r < 4; ++r) {
          float s = g0[r].f[0] + g0[r].f[1] + g1[r].f[0] + g1[r].f[1];
          s += __shfl_xor(s, 1, 16); s += __shfl_xor(s, 2, 16);
          s += __shfl_xor(s, 4, 16); s += __shfl_xor(s, 8, 16);
          int b2 = rg * 16 + lhi * 4 + r;
          __builtin_nontemporal_store(eo[r] / s,
            &outp[(size_t)(t - 1) * BB * VV + (size_t)b2 * VV + cg * 16 + llo]);
        }
      }

      // ---- bar2 post: e2 + psumB (+outp) drained, flag = 2t+2 ----
      __syncthreads();   // S7
      if (tid == 0) st32c(myflags + cg * 32, 2u * (unsigned)t + 2u);
    } else {
      // t == LL: certify psumO(LL) via all-64 bar1(LL), emit out(LL-1)
      if (wave == 3) {
        POLL64(myflags, 2u * (unsigned)t + 1u);
        #pragma unroll
        for (int r = 0; r < 4; ++r) {
          const float* pp = psumO + rg * 1024 + (lhi * 4 + r) * 64 + llo * 4;
          union { unsigned long long u; float f[2]; } c0, c1;
          c0.u = ld64c(pp); c1.u = ld64c(pp + 2);
          float s = c0.f[0] + c0.f[1] + c1.f[0] + c1.f[1];
          s += __shfl_xor(s, 1, 16); s += __shfl_xor(s, 2, 16);
          s += __shfl_xor(s, 4, 16); s += __shfl_xor(s, 8, 16);
          int b2 = rg * 16 + lhi * 4 + r;
          outp[(size_t)(t - 1) * BB * VV + (size_t)b2 * VV + cg * 16 + llo] = eo[r] / s;
        }
      }
    }
  }
}

// ---------------- host launcher ----------------

extern "C" void kernel_launch(void* const* d_in, const int* in_sizes, int n_in,
                              void* d_out, int out_size, void* d_ws, size_t ws_size,
                              hipStream_t stream) {
  (void)in_sizes; (void)n_in; (void)out_size; (void)ws_size;
  const float* enc    = (const float*)d_in[0];
  const float* hidden = (const float*)d_in[1];
  const float* dec0   = (const float*)d_in[2];
  const float* Wa     = (const float*)d_in[3];
  // d_in[4] = ba: unused (softmax shift-invariance)
  const float* v      = (const float*)d_in[5];
  const float* W_ih   = (const float*)d_in[6];
  const float* b_ih   = (const float*)d_in[7];
  const float* W_hh   = (const float*)d_in[8];
  const float* b_hh   = (const float*)d_in[9];
  const float* Wo     = (const float*)d_in[10];
  const float* bo     = (const float*)d_in[11];
  const float* Wf     = (const float*)d_in[12];
  const float* bfv    = (const float*)d_in[13];

  char* ws = (char*)d_ws;
  float* ve    = (float*)(ws + OFF_VE);
  float* es    = (float*)(ws + OFF_ES);
  float* attn  = (float*)(ws + OFF_A);
  float* ctx   = (float*)(ws + OFF_CTX);
  float* gictx = (float*)(ws + OFF_GICTX);
  float* oc    = (float*)(ws + OFF_OC);
  unsigned* flags = (unsigned*)(ws + OFF_FLAGS);
  float* psumB = (float*)(ws + OFF_PSUMB);
  float* psumO = (float*)(ws + OFF_PSUMO);
  short* e2a   = (short*)(ws + OFF_E2A);
  short* e2b   = (short*)(ws + OFF_E2B);
  short* hb    = (short*)(ws + OFF_HB);
  short* packW = (short*)(ws + OFF_PACKW);

  hipLaunchKernelGGL(K_init, dim3(256), dim3(256), 0, stream, hidden, dec0, hb, e2a, flags);
  hipLaunchKernelGGL(K_ve, dim3(16), dim3(64), 0, stream, Wa, v, ve);
  hipLaunchKernelGGL(K_escore, dim3(LL * BB), dim3(64), 0, stream, enc, ve, es);
  hipLaunchKernelGGL(K_asm, dim3(BB), dim3(256), 0, stream, es, attn);
  hipLaunchKernelGGL(K_ctx, dim3(512), dim3(128), 0, stream, enc, attn, ctx);
  hipLaunchKernelGGL(K_gictx, dim3(4096), dim3(64), 0, stream, ctx, W_ih, b_ih, Wo, bo, gictx, oc);
  hipLaunchKernelGGL(K_pack, dim3(64 * 9 * 32), dim3(64), 0, stream, W_ih, W_hh, Wo, Wf, packW);
  hipLaunchKernelGGL(K_step, dim3(256), dim3(256), 0, stream,
                     (const bf16x8*)packW, e2a, e2b, hb, hidden, psumB, psumO,
                     gictx, oc, b_hh, bfv, (float*)d_out, flags);
}

// Round 9
// 5423.716 us; speedup vs baseline: 3.0459x; 1.2018x over previous
//
#include <hip/hip_runtime.h>
#include <hip/hip_bf16.h>

// Decoder: attention is step-invariant (softmax shift-invariance) => ctx
// precomputed once. Persistent kernel runs the 512-step GRU recurrence.
// R13 = R12's gated-stage architecture with the access-pattern bug fixed
// and phase B made WAVE-LOCAL:
//  - STAGE_BLOCK fixed: lane -> row lane>>2, QUAD-CONTIGUOUS 16B columns
//    (R12 had quad lanes striding 128B -> 4-way LDS bank conflicts, the
//    1.24e8 -> 3.26e8 SQ_LDS_BANK_CONFLICT spike, + uncoalesced loads).
//  - A-gate: wave0 = R9 path (POLL64 + pre-stage psumB issue); waves 1-3
//    poll only their 16 rotated sources. S1 is collective all-64 cert
//    (4 waves x 4 distinct blocks). Post-poll barrier gone.
//  - phase B: wave w's MFMA consumes EXACTLY h-block w (ks=8w..8w+8 ->
//    cols 256w..256w+256 = sources 16w..16w+16). So each wave polls its
//    16 sources, stages ITS block, and runs MFMA with NO barrier. wave3
//    polls all-64 (psumO certification) and prefetches the psumO gather
//    under its MFMAs. 8 syncs/step -> 5.
//  - e2 + psumB parity double-buffered (writer at t passed S1(t) =>
//    collective all-64 bar2(t-1) => all prior readers done). h single-
//    buffered (readers gate on exact sources; overwrite ordered behind
//    collective bar2(t-1)). outp stores nontemporal.
// Lessons: R5 poll cheap/load once; R8 no whole-cache fences; R10 no
// plain-store publish; R11 topology pinned by weight residency (256thr).

#define HH 1024
#define BB 64
#define LL 512
#define VV 1024

typedef short bf16x8 __attribute__((ext_vector_type(8)));
typedef float f32x4 __attribute__((ext_vector_type(4)));

__device__ __forceinline__ short f2bf(float x) {
  union { float f; unsigned u; } a; a.f = x;
  unsigned r = (a.u + 0x7FFF + ((a.u >> 16) & 1)) >> 16;
  return (short)r;
}

__device__ __forceinline__ float fsig(float x) {      // sigmoid, saturation-safe
  return 1.0f / (1.0f + __expf(-x));
}
__device__ __forceinline__ float ftanh(float x) {     // tanh, saturation-safe
  float ex = __expf(2.0f * x);
  return 1.0f - 2.0f / (ex + 1.0f);
}

// ---- coherent (cross-XCD, L3-point) access helpers ----
__device__ __forceinline__ unsigned long long ld64c(const void* p) {
  return __hip_atomic_load((const unsigned long long*)p, __ATOMIC_RELAXED, __HIP_MEMORY_SCOPE_AGENT);
}
__device__ __forceinline__ unsigned ld32c(const void* p) {
  return __hip_atomic_load((const unsigned*)p, __ATOMIC_RELAXED, __HIP_MEMORY_SCOPE_AGENT);
}
__device__ __forceinline__ void st32c(void* p, unsigned v) {
  __hip_atomic_store((unsigned*)p, v, __ATOMIC_RELAXED, __HIP_MEMORY_SCOPE_AGENT);
}
__device__ __forceinline__ void stfc(float* p, float v) {
  union { float f; unsigned u; } a; a.f = v;
  st32c(p, a.u);
}

// ---------------- workspace layout (bytes) ----------------
// FLAGS: 4 rg * 64 cg * 128B (one line per WG) = 32 KB
static constexpr size_t OFF_VE    = 0;                       // 1024 f32
static constexpr size_t OFF_ES    = 4096;                    // 64*512 f32
static constexpr size_t OFF_A     = OFF_ES    + 131072;      // 64*512 f32
static constexpr size_t OFF_CTX   = OFF_A     + 131072;      // 64*1024 f32
static constexpr size_t OFF_GICTX = OFF_CTX   + 262144;      // 64*3072 f32
static constexpr size_t OFF_OC    = OFF_GICTX + 786432;      // 64*1024 f32
static constexpr size_t OFF_FLAGS = OFF_OC    + 262144;      // 8192 u32 (one/128B)
static constexpr size_t OFF_PSUMB = OFF_FLAGS + 32768;       // 2 x 4096 f32 (parity)
static constexpr size_t OFF_PSUMO = OFF_PSUMB + 32768;       // 4rg*16row*64cg f32
static constexpr size_t OFF_E2A   = OFF_PSUMO + 16384;       // 64*1024 bf16 (EB0)
static constexpr size_t OFF_HB    = OFF_E2A   + 131072;      // 64*1024 bf16 (h)
static constexpr size_t OFF_E2B   = OFF_HB    + 131072;      // 64*1024 bf16 (EB1)
static constexpr size_t OFF_PACKW = OFF_E2B   + 131072;      // 18 MB packed weights

// ---------------- precompute kernels ----------------

__global__ void K_init(const float* __restrict__ hidden, const float* __restrict__ dec0,
                       short* __restrict__ hb, short* __restrict__ e2a,
                       unsigned* __restrict__ flags) {
  int tid = blockIdx.x * 256 + threadIdx.x;  // grid 256 -> 65536 threads
  if (tid < BB * HH) {
    hb[tid] = f2bf(hidden[tid]);
    e2a[tid] = f2bf(dec0[tid]);
  }
  if (tid < 8192) flags[tid] = 0u;
}

__global__ void K_ve(const float* __restrict__ Wa, const float* __restrict__ v, float* __restrict__ ve) {
  int i = blockIdx.x * 64 + threadIdx.x;  // 1024 threads
  float acc = 0.f;
  for (int k = 0; k < HH; ++k) acc += Wa[(size_t)k * 2048 + 1024 + i] * v[k];
  ve[i] = acc;
}

__global__ void K_escore(const float* __restrict__ enc, const float* __restrict__ ve, float* __restrict__ es) {
  int bid = blockIdx.x;           // 0..32767 = l*64+b
  int lane = threadIdx.x;         // 64
  const float* row = enc + (size_t)bid * HH;
  float acc = 0.f;
  #pragma unroll
  for (int i = 0; i < 16; ++i) { int k = lane + 64 * i; acc += row[k] * ve[k]; }
  for (int m = 1; m < 64; m <<= 1) acc += __shfl_xor(acc, m);
  if (lane == 0) { int l = bid >> 6, b = bid & 63; es[b * LL + l] = acc; }
}

__global__ void K_asm(const float* __restrict__ es, float* __restrict__ a) {
  __shared__ float red[256];
  int b = blockIdx.x, tid = threadIdx.x;
  float e0 = es[b * LL + tid], e1 = es[b * LL + 256 + tid];
  red[tid] = fmaxf(e0, e1);
  __syncthreads();
  for (int s = 128; s > 0; s >>= 1) { if (tid < s) red[tid] = fmaxf(red[tid], red[tid + s]); __syncthreads(); }
  float M = red[0];
  __syncthreads();
  float x0 = expf(e0 - M), x1 = expf(e1 - M);
  red[tid] = x0 + x1;
  __syncthreads();
  for (int s = 128; s > 0; s >>= 1) { if (tid < s) red[tid] += red[tid + s]; __syncthreads(); }
  float S = red[0];
  a[b * LL + tid] = x0 / S;
  a[b * LL + 256 + tid] = x1 / S;
}

__global__ void K_ctx(const float* __restrict__ enc, const float* __restrict__ a, float* __restrict__ ctx) {
  int b = blockIdx.x >> 3, hc = blockIdx.x & 7;  // 512 blocks, 128 thr
  int h = hc * 128 + threadIdx.x;
  float acc = 0.f;
  for (int l = 0; l < LL; ++l) acc += a[b * LL + l] * enc[(size_t)(l * BB + b) * HH + h];
  ctx[b * HH + h] = acc;
}

__global__ void K_gictx(const float* __restrict__ ctx, const float* __restrict__ W_ih, const float* __restrict__ b_ih,
                        const float* __restrict__ Wo, const float* __restrict__ bo,
                        float* __restrict__ gictx, float* __restrict__ oc) {
  int c = blockIdx.x;      // 4096 blocks
  int b = threadIdx.x;     // 64 threads
  float acc = 0.f;
  if (c < 3072) {
    for (int k = 0; k < HH; ++k) acc += ctx[b * HH + k] * W_ih[(size_t)c * 2048 + 1024 + k];
    gictx[b * 3072 + c] = acc + b_ih[c];
  } else {
    int c2 = c - 3072;
    for (int k = 0; k < HH; ++k) acc += ctx[b * HH + k] * Wo[(size_t)c2 * 3072 + 2048 + k];
    oc[b * HH + c2] = acc + bo[c2];
  }
}

// Pack weights into MFMA B-fragment layout, bf16.
// tiles per col-group cg (16 cols): 0:gi_r(W1) 1:gi_z 2:gi_n 3:Wo_d 4:gh_r(Whh) 5:gh_z 6:gh_n 7:Wf 8:Wo_h
__global__ void K_pack(const float* __restrict__ W_ih, const float* __restrict__ W_hh,
                       const float* __restrict__ Wo, const float* __restrict__ Wf, short* __restrict__ packW) {
  int tid = blockIdx.x * 64 + threadIdx.x;   // 64*9*32*64 = 1,179,648
  int lane = tid & 63;
  int ks = (tid >> 6) & 31;
  int tile = (tid >> 11) % 9;
  int cg = tid / (9 * 32 * 64);
  int n = lane & 15;
  int k0 = ks * 32 + (lane >> 4) * 8;
  int row = cg * 16 + n;
  const float* src;
  size_t base;
  switch (tile) {
    case 0: base = (size_t)row * 2048;               src = W_ih; break;
    case 1: base = (size_t)(1024 + row) * 2048;      src = W_ih; break;
    case 2: base = (size_t)(2048 + row) * 2048;      src = W_ih; break;
    case 3: base = (size_t)row * 3072 + 1024;        src = Wo;   break;
    case 4: base = (size_t)row * 1024;               src = W_hh; break;
    case 5: base = (size_t)(1024 + row) * 1024;      src = W_hh; break;
    case 6: base = (size_t)(2048 + row) * 1024;      src = W_hh; break;
    case 7: base = (size_t)row * 1024;               src = Wf;   break;
    default: base = (size_t)row * 3072;              src = Wo;   break;
  }
  bf16x8 vv;
  #pragma unroll
  for (int j = 0; j < 8; ++j) vv[j] = f2bf(src[base + k0 + j]);
  ((bf16x8*)packW)[tid] = vv;
}

// ---------------- persistent step kernel ----------------

// Stage one 16-row x 256-col (16-cg) block into LDS with XOR-swizzle
// byte_col ^= ((row&7)<<4). Lane -> row lane>>2; quad lanes contiguous
// 16B columns (coalesced 64B/row/instr); iterate columns +64B x8.
#define STAGE_BLOCK(dst, srcbase, blk)                                         \
  do {                                                                         \
    const int r_ = lane >> 2;                                                  \
    const int co_ = ((blk) << 8) + ((lane & 3) << 3);   /* shorts in row */    \
    const short* p_ = (srcbase) + (r_ << 10) + co_;                            \
    f32x4 t0_, t1_, t2_, t3_, t4_, t5_, t6_, t7_;                              \
    asm volatile(                                                              \
      "global_load_dwordx4 %0, %8, off sc0 sc1\n\t"                            \
      "global_load_dwordx4 %1, %8, off offset:64 sc0 sc1\n\t"                  \
      "global_load_dwordx4 %2, %8, off offset:128 sc0 sc1\n\t"                 \
      "global_load_dwordx4 %3, %8, off offset:192 sc0 sc1\n\t"                 \
      "global_load_dwordx4 %4, %8, off offset:256 sc0 sc1\n\t"                 \
      "global_load_dwordx4 %5, %8, off offset:320 sc0 sc1\n\t"                 \
      "global_load_dwordx4 %6, %8, off offset:384 sc0 sc1\n\t"                 \
      "global_load_dwordx4 %7, %8, off offset:448 sc0 sc1\n\t"                 \
      "s_waitcnt vmcnt(0)"                                                     \
      : "=&v"(t0_), "=&v"(t1_), "=&v"(t2_), "=&v"(t3_),                        \
        "=&v"(t4_), "=&v"(t5_), "=&v"(t6_), "=&v"(t7_)                         \
      : "v"(p_)                                                                \
      : "memory");                                                             \
    f32x4 tv_[8] = {t0_, t1_, t2_, t3_, t4_, t5_, t6_, t7_};                   \
    _Pragma("unroll")                                                          \
    for (int i_ = 0; i_ < 8; ++i_) {                                           \
      int bc_ = (co_ << 1) + (i_ << 6);                                        \
      int sw_ = bc_ ^ ((r_ & 7) << 4);                                         \
      *(f32x4*)&(dst)[(r_ << 10) + (sw_ >> 1)] = tv_[i_];                      \
    }                                                                          \
    __builtin_amdgcn_sched_barrier(0);                                         \
  } while (0)

// Poll the 16 source-cg flags of block blk (4-way redundant across lanes).
#define POLL16(flg, blk, ep)                                                   \
  do {                                                                         \
    unsigned f_;                                                               \
    for (;;) {                                                                 \
      f_ = ld32c((flg) + ((blk) * 16 + (lane & 15)) * 32);                     \
      if (!__any(f_ < (unsigned)(ep))) break;                                  \
      __builtin_amdgcn_s_sleep(1);                                             \
    }                                                                          \
  } while (0)

// Poll all 64 flags (one line per lane).
#define POLL64(flg, ep)                                                        \
  do {                                                                         \
    unsigned f_;                                                               \
    for (;;) {                                                                 \
      f_ = ld32c((flg) + lane * 32);                                           \
      if (!__any(f_ < (unsigned)(ep))) break;                                  \
      __builtin_amdgcn_s_sleep(1);                                             \
    }                                                                          \
  } while (0)

// MFMA A-fragment read from swizzled LDS slice (conflict-free, 2-way max).
#define LFRAG(buf, ks) \
  (*(const bf16x8*)&(buf)[((llo) << 10) + (((((ks) * 64) + (lhi << 4)) ^ ((llo & 7) << 4)) >> 1)])

__global__ __launch_bounds__(256, 1) void K_step(
    const bf16x8* __restrict__ packW,
    short* __restrict__ e2a, short* __restrict__ e2b,
    short* __restrict__ hb,
    const float* __restrict__ hidden,
    float* __restrict__ psumB, float* __restrict__ psumO,
    const float* __restrict__ gictx, const float* __restrict__ ocbuf,
    const float* __restrict__ b_hh, const float* __restrict__ bfv,
    float* __restrict__ outp, unsigned* __restrict__ flags) {
  const int wg = blockIdx.x;
  const int rg = wg & 3;      // row group: rows [16rg,16rg+16)
  const int cg = wg >> 2;     // col group: 16 cols of each output tile
  const int tid = threadIdx.x;
  const int wave = tid >> 6;
  const int lane = tid & 63;
  const int lhi = lane >> 4;
  const int llo = lane & 15;
  const int blkA = (wave + cg) & 3;   // rotated source block for A-stage

  __shared__ short se2[16 * 1024];    // e2(t) slice, swizzled (32KB)
  __shared__ short sh[16 * 1024];     // h(t)/h_new slice, swizzled (32KB)
  __shared__ float lds_g[6][16][17];  // raw gate accs: gi_r gi_z gi_n gh_r gh_z gh_n
  __shared__ float lds_p[5][16][17];  // phase-B partials [0..3] + savedA2 [4]
  __shared__ float lds_rs[16];        // 1/sum per row (e2 normalization)

  const int wbase = cg * (9 * 32 * 64) + lane;
  const int t0 = wave * 2, t1 = wave * 2 + 1;

  // ---- load step-invariant weights, then FORCE them resident ----
  bf16x8 wA0[32], wA1[32], wB8[8];
  #pragma unroll
  for (int ks = 0; ks < 32; ++ks) {
    wA0[ks] = packW[wbase + (t0 * 32 + ks) * 64];
    wA1[ks] = packW[wbase + (t1 * 32 + ks) * 64];
  }
  #pragma unroll
  for (int i = 0; i < 8; ++i) wB8[i] = packW[wbase + (8 * 32 + wave * 8 + i) * 64];
  #pragma unroll
  for (int ks = 0; ks < 32; ++ks) {
    asm volatile("" : "+v"(wA0[ks]));
    asm volatile("" : "+v"(wA1[ks]));
  }
  #pragma unroll
  for (int i = 0; i < 8; ++i) asm volatile("" : "+v"(wB8[i]));

  // ---- step-invariant per-thread scalars; h carried in-register ----
  const int row = tid >> 4, col = tid & 15;
  const int b_ = rg * 16 + row, j = cg * 16 + col;
  const float c_gr  = gictx[b_ * 3072 + j]        + b_hh[j];
  const float c_gz  = gictx[b_ * 3072 + 1024 + j] + b_hh[1024 + j];
  const float c_gn  = gictx[b_ * 3072 + 2048 + j];
  const float c_ghn = b_hh[2048 + j];
  const float c_oc  = ocbuf[b_ * HH + j];
  float h_reg = hidden[b_ * HH + j];
  const float c_bf  = bfv[cg * 16 + llo];

  // one flag per 128B line: flags[(rg*64 + cg) * 32]
  unsigned* myflags = flags + rg * (64 * 32);
  short* hslice = hb + rg * 16384;

  // pre-stage h(0) into lds (B-stage keeps it current afterwards)
  STAGE_BLOCK(sh, hslice, wave);

  for (int t = 0; t <= LL; ++t) {
    const int par = t & 1;
    const short* ebr = (par ? e2b : e2a) + rg * 16384;  // EB[par]: e2(t)
    short* ebw = par ? e2a : e2b;                        // EB[par^1]: e2(t+1)
    const float* PBr = psumB + par * 4096 + rg * 1024;
    float* PBw = psumB + (par ^ 1) * 4096 + rg * 1024;

    // ======== A-gate + stage e2(t) ========
    unsigned long long pc[8];
    if (wave == 0) {
      POLL64(myflags, 2u * (unsigned)t);          // bar2(t-1), all 64 (psumB)
      if (t >= 1) {
        const float* pp = PBr + llo * 64 + lhi * 16;
        #pragma unroll
        for (int i = 0; i < 8; ++i) pc[i] = ld64c(pp + i * 2);
      }
      STAGE_BLOCK(se2, ebr, blkA);
    } else {
      POLL16(myflags, blkA, 2u * (unsigned)t);    // only this block's sources
      STAGE_BLOCK(se2, ebr, blkA);
    }
    __syncthreads();   // S1: all 4 blocks staged; collective all-64 cert

    // wave0: psumB reduce + lds_rs (hidden under other waves' phase-A MFMAs)
    if (wave == 0) {
      float total = 1.0f;
      if (t >= 1) {
        float s = 0.f;
        #pragma unroll
        for (int i = 0; i < 8; ++i) {
          union { unsigned long long u; float f[2]; } c; c.u = pc[i];
          s += c.f[0] + c.f[1];
        }
        s += __shfl_xor(s, 16);
        s += __shfl_xor(s, 32);
        total = s;
      }
      if (lane < 16) lds_rs[lane] = 1.0f / total;
    }

    // ================= PHASE A =================
    // waves: 0:{gi_r,gi_z}(A=e2) 1:{gi_n,Wo_d}(A=e2) 2:{gh_r,gh_z}(A=h) 3:{gh_n(A=h), Wf(A=e2)}
    const short* A0 = (wave < 2) ? se2 : sh;
    f32x4 acc0 = {0.f, 0.f, 0.f, 0.f}, acc1 = {0.f, 0.f, 0.f, 0.f};
    #pragma unroll
    for (int ks = 0; ks < 32; ++ks) {
      bf16x8 af0 = LFRAG(A0, ks);
      bf16x8 af1 = (wave == 3) ? LFRAG(se2, ks) : af0;
      acc0 = __builtin_amdgcn_mfma_f32_16x16x32_bf16(af0, wA0[ks], acc0, 0, 0, 0);
      acc1 = __builtin_amdgcn_mfma_f32_16x16x32_bf16(af1, wA1[ks], acc1, 0, 0, 0);
    }

    // stash raw accumulators to LDS
    f32x4 savedA2;
    if (wave == 0) {
      #pragma unroll
      for (int r = 0; r < 4; ++r) { lds_g[0][lhi*4+r][llo] = acc0[r]; lds_g[1][lhi*4+r][llo] = acc1[r]; }
    } else if (wave == 1) {
      #pragma unroll
      for (int r = 0; r < 4; ++r) { lds_g[2][lhi*4+r][llo] = acc0[r]; savedA2[r] = acc1[r]; }
    } else if (wave == 2) {
      #pragma unroll
      for (int r = 0; r < 4; ++r) { lds_g[3][lhi*4+r][llo] = acc0[r]; lds_g[4][lhi*4+r][llo] = acc1[r]; }
    } else {
      #pragma unroll
      for (int r = 0; r < 4; ++r) lds_g[5][lhi*4+r][llo] = acc0[r];
    }
    __syncthreads();   // S2: lds_g + lds_rs visible

    // wave3: out logits -> eo, psumO partials (distinct slots, no atomics)
    f32x4 eo = {0.f, 0.f, 0.f, 0.f};
    if (wave == 3 && t >= 1) {
      #pragma unroll
      for (int r = 0; r < 4; ++r) eo[r] = __expf(acc1[r] * lds_rs[lhi*4+r] + c_bf);
      #pragma unroll
      for (int r = 0; r < 4; ++r) {
        float v_ = eo[r];
        v_ += __shfl_xor(v_, 1, 16); v_ += __shfl_xor(v_, 2, 16);
        v_ += __shfl_xor(v_, 4, 16); v_ += __shfl_xor(v_, 8, 16);
        if (llo == 0) stfc(psumO + rg * 1024 + (lhi*4+r) * 64 + cg, v_);
      }
    }

    // GRU elementwise: thread (row,col) owns h[b_,j]
    {
      float rsr = lds_rs[row];
      float gr  = lds_g[0][row][col] * rsr + lds_g[3][row][col] + c_gr;
      float gz  = lds_g[1][row][col] * rsr + lds_g[4][row][col] + c_gz;
      float gin = lds_g[2][row][col] * rsr + c_gn;
      float ghn = lds_g[5][row][col] + c_ghn;
      float rr = fsig(gr);
      float zz = fsig(gz);
      float nn = ftanh(gin + rr * ghn);
      float hnew = (1.0f - zz) * nn + zz * h_reg;
      h_reg = hnew;
      unsigned short hv = (unsigned short)f2bf(hnew);
      int other = __shfl_xor((int)hv, 1);
      if ((col & 1) == 0) {
        unsigned pk = (unsigned)hv | ((unsigned)(unsigned short)other << 16);
        st32c(hb + b_ * HH + (j & ~1), pk);
      }
    }

    // ---- bar1 post: h_new + psumO drained, flag = 2t+1 ----
    __syncthreads();   // S3: drains h + psumO stores
    if (tid == 0) st32c(myflags + cg * 32, 2u * (unsigned)t + 1u);

    if (t < LL) {
      // ======== B-gate + stage h(t+1), WAVE-LOCAL (block = wave) ========
      union { unsigned long long u; float f[2]; } g0[4], g1[4];
      if (wave == 3) {
        POLL64(myflags, 2u * (unsigned)t + 1u);   // all-64: certifies psumO too
        STAGE_BLOCK(sh, hslice, 3);
        if (t >= 1) {                             // prefetch psumO under MFMAs
          #pragma unroll
          for (int r = 0; r < 4; ++r) {
            const float* pp = psumO + rg * 1024 + (lhi * 4 + r) * 64 + llo * 4;
            g0[r].u = ld64c(pp);
            g1[r].u = ld64c(pp + 2);
          }
        }
      } else {
        POLL16(myflags, wave, 2u * (unsigned)t + 1u);  // exactly MY sources
        STAGE_BLOCK(sh, hslice, wave);
      }

      // ================= PHASE B (no barrier: wave w consumes block w) ====
      f32x4 accB = {0.f, 0.f, 0.f, 0.f};
      #pragma unroll
      for (int i = 0; i < 8; ++i) {
        int ks = wave * 8 + i;
        bf16x8 af = LFRAG(sh, ks);
        accB = __builtin_amdgcn_mfma_f32_16x16x32_bf16(af, wB8[i], accB, 0, 0, 0);
      }
      #pragma unroll
      for (int r = 0; r < 4; ++r) lds_p[wave][lhi*4+r][llo] = accB[r];
      if (wave == 1) {
        #pragma unroll
        for (int r = 0; r < 4; ++r) lds_p[4][lhi*4+r][llo] = savedA2[r];
      }
      __syncthreads();   // S6: lds_p visible (+ all sh blocks staged)
      {
        float rsr = lds_rs[row];
        float l2 = lds_p[0][row][col] + lds_p[1][row][col] + lds_p[2][row][col] + lds_p[3][row][col]
                 + lds_p[4][row][col] * rsr + c_oc;
        float ev = __expf(l2);
        unsigned short eb = (unsigned short)f2bf(ev);
        int other = __shfl_xor((int)eb, 1);
        if ((col & 1) == 0) {
          unsigned pk = (unsigned)eb | ((unsigned)(unsigned short)other << 16);
          st32c(ebw + b_ * HH + (j & ~1), pk);
        }
        float sv = ev;
        sv += __shfl_xor(sv, 1, 16); sv += __shfl_xor(sv, 2, 16);
        sv += __shfl_xor(sv, 4, 16); sv += __shfl_xor(sv, 8, 16);
        if (col == 0) stfc(PBw + row * 64 + cg, sv);
      }

      // out(t-1): reduce prefetched psumO, nontemporal store
      if (wave == 3 && t >= 1) {
        #pragma unroll
        for (int r = 0; r < 4; ++r) {
          float s = g0[r].f[0] + g0[r].f[1] + g1[r].f[0] + g1[r].f[1];
          s += __shfl_xor(s, 1, 16); s += __shfl_xor(s, 2, 16);
          s += __shfl_xor(s, 4, 16); s += __shfl_xor(s, 8, 16);
          int b2 = rg * 16 + lhi * 4 + r;
          __builtin_nontemporal_store(eo[r] / s,
            &outp[(size_t)(t - 1) * BB * VV + (size_t)b2 * VV + cg * 16 + llo]);
        }
      }

      // ---- bar2 post: e2 + psumB (+outp) drained, flag = 2t+2 ----
      __syncthreads();   // S7
      if (tid == 0) st32c(myflags + cg * 32, 2u * (unsigned)t + 2u);
    } else {
      // t == LL: certify psumO(LL) via all-64 bar1(LL), emit out(LL-1)
      if (wave == 3) {
        POLL64(myflags, 2u * (unsigned)t + 1u);
        #pragma unroll
        for (int r = 0; r < 4; ++r) {
          const float* pp = psumO + rg * 1024 + (lhi * 4 + r) * 64 + llo * 4;
          union { unsigned long long u; float f[2]; } c0, c1;
          c0.u = ld64c(pp); c1.u = ld64c(pp + 2);
          float s = c0.f[0] + c0.f[1] + c1.f[0] + c1.f[1];
          s += __shfl_xor(s, 1, 16); s += __shfl_xor(s, 2, 16);
          s += __shfl_xor(s, 4, 16); s += __shfl_xor(s, 8, 16);
          int b2 = rg * 16 + lhi * 4 + r;
          outp[(size_t)(t - 1) * BB * VV + (size_t)b2 * VV + cg * 16 + llo] = eo[r] / s;
        }
      }
    }
  }
}

// ---------------- host launcher ----------------

extern "C" void kernel_launch(void* const* d_in, const int* in_sizes, int n_in,
                              void* d_out, int out_size, void* d_ws, size_t ws_size,
                              hipStream_t stream) {
  (void)in_sizes; (void)n_in; (void)out_size; (void)ws_size;
  const float* enc    = (const float*)d_in[0];
  const float* hidden = (const float*)d_in[1];
  const float* dec0   = (const float*)d_in[2];
  const float* Wa     = (const float*)d_in[3];
  // d_in[4] = ba: unused (softmax shift-invariance)
  const float* v      = (const float*)d_in[5];
  const float* W_ih   = (const float*)d_in[6];
  const float* b_ih   = (const float*)d_in[7];
  const float* W_hh   = (const float*)d_in[8];
  const float* b_hh   = (const float*)d_in[9];
  const float* Wo     = (const float*)d_in[10];
  const float* bo     = (const float*)d_in[11];
  const float* Wf     = (const float*)d_in[12];
  const float* bfv    = (const float*)d_in[13];

  char* ws = (char*)d_ws;
  float* ve    = (float*)(ws + OFF_VE);
  float* es    = (float*)(ws + OFF_ES);
  float* attn  = (float*)(ws + OFF_A);
  float* ctx   = (float*)(ws + OFF_CTX);
  float* gictx = (float*)(ws + OFF_GICTX);
  float* oc    = (float*)(ws + OFF_OC);
  unsigned* flags = (unsigned*)(ws + OFF_FLAGS);
  float* psumB = (float*)(ws + OFF_PSUMB);
  float* psumO = (float*)(ws + OFF_PSUMO);
  short* e2a   = (short*)(ws + OFF_E2A);
  short* e2b   = (short*)(ws + OFF_E2B);
  short* hb    = (short*)(ws + OFF_HB);
  short* packW = (short*)(ws + OFF_PACKW);

  hipLaunchKernelGGL(K_init, dim3(256), dim3(256), 0, stream, hidden, dec0, hb, e2a, flags);
  hipLaunchKernelGGL(K_ve, dim3(16), dim3(64), 0, stream, Wa, v, ve);
  hipLaunchKernelGGL(K_escore, dim3(LL * BB), dim3(64), 0, stream, enc, ve, es);
  hipLaunchKernelGGL(K_asm, dim3(BB), dim3(256), 0, stream, es, attn);
  hipLaunchKernelGGL(K_ctx, dim3(512), dim3(128), 0, stream, enc, attn, ctx);
  hipLaunchKernelGGL(K_gictx, dim3(4096), dim3(64), 0, stream, ctx, W_ih, b_ih, Wo, bo, gictx, oc);
  hipLaunchKernelGGL(K_pack, dim3(64 * 9 * 32), dim3(64), 0, stream, W_ih, W_hh, Wo, Wf, packW);
  hipLaunchKernelGGL(K_step, dim3(256), dim3(256), 0, stream,
                     (const bf16x8*)packW, e2a, e2b, hb, hidden, psumB, psumO,
                     gictx, oc, b_hh, bfv, (float*)d_out, flags);
}